// Round 2
// baseline (420.330 us; speedup 1.0000x reference)
//
#include <hip/hip_runtime.h>
#include <hip/hip_bf16.h>

typedef unsigned short u16;
typedef unsigned int u32;
typedef __bf16 bf16x8 __attribute__((ext_vector_type(8)));
typedef float f32x4 __attribute__((ext_vector_type(4)));

#define AS1(p) ((const __attribute__((address_space(1))) void*)(p))
#define AS3(p) ((__attribute__((address_space(3))) void*)(p))

#define BATCH 128
#define TOK   256
#define NH    16
#define HD    32
#define CDIM  512
#define QKVC  1536
#define SCALE 0.17677669529663687f

__device__ __forceinline__ u16 f2b(float f) {
  unsigned u = __float_as_uint(f);
  unsigned r = (u + 0x7fffu + ((u >> 16) & 1u)) >> 16;
  return (u16)r;
}
__device__ __forceinline__ u16 f2bc(float f) {   // let compiler pick cvt instr
  __bf16 h = (__bf16)f;
  u16 u;
  __builtin_memcpy(&u, &h, 2);
  return u;
}

// ---------------- fp32 -> bf16 conversion ----------------
__global__ __launch_bounds__(256) void cvt_bf16_kernel(const float* __restrict__ in,
                                                       u16* __restrict__ out, int n) {
  int i = (blockIdx.x * 256 + threadIdx.x) * 8;
  if (i >= n) return;
  float4 a = *(const float4*)(in + i);
  float4 b = *(const float4*)(in + i + 4);
  u16 h[8];
  h[0] = f2b(a.x); h[1] = f2b(a.y); h[2] = f2b(a.z); h[3] = f2b(a.w);
  h[4] = f2b(b.x); h[5] = f2b(b.y); h[6] = f2b(b.z); h[7] = f2b(b.w);
  *(uint4*)(out + i) = *(const uint4*)h;
}

// ---------------- bias2: per-lane fragment layout, bf16 ----------------
// bias2[((h*16 + rb)*64 + lane)*64 + t*4 + r] = biasT[h][n][m],
//   n = rb*16 + (lane>>4)*4 + r, m = t*16 + (lane&15)
__global__ __launch_bounds__(256) void build_bias2_kernel(const float* __restrict__ rpb,
                                                          u16* __restrict__ bias2) {
  int i = blockIdx.x * 256 + threadIdx.x;   // 16*16*64*64 = 2^20
  int tr = i & 63, lane = (i >> 6) & 63, rb = (i >> 12) & 15, h = i >> 16;
  int t = tr >> 2, r = tr & 3;
  int n = rb * 16 + (lane >> 4) * 4 + r;
  int m = t * 16 + (lane & 15);
  int idx = ((n >> 4) - (m >> 4) + 15) * 31 + ((n & 15) - (m & 15) + 15);
  bias2[i] = f2b(rpb[idx * 16 + h]);
}

// ---------------- mod2: per-lane fragment layout, bf16 ----------------
// mod2[(rb*64 + lane)*64 + t*4 + r] = mod[n][m]
__global__ __launch_bounds__(256) void build_mod2_kernel(u16* __restrict__ mod2) {
  int i = blockIdx.x * 256 + threadIdx.x;   // 16*64*64 = 65536
  int tr = i & 63, lane = (i >> 6) & 63, rb = i >> 12;
  int t = tr >> 2, r = tr & 3;
  int n = rb * 16 + (lane >> 4) * 4 + r;
  int m = t * 16 + (lane & 15);
  int dr = (n >> 4) - (m >> 4), dc = (n & 15) - (m & 15);
  int d2 = dr * dr + dc * dc;
  float val = 0.0f;
  if (d2 <= 229) {   // exact integer form of (m >= bound); boundary at d2==229
    const float fc = 6.2831853071795864f / (60.0f * 1.4142135623730951f);
    val = expf(cosf(fc * sqrtf((float)d2))) * 0.5f;
  }
  mod2[i] = f2b(val);
}

// ---------------- bf16 GEMM: out = A[M,K] @ Bt[N,K]^T (+bias epilogue) ----------------
template<int NDIM, int MODE>
__global__ __launch_bounds__(256) void gemm_bt(const u16* __restrict__ A,
                                               const u16* __restrict__ Bt,
                                               const float* __restrict__ bvec,
                                               void* __restrict__ outp) {
  constexpr int K = 512;
  __shared__ __align__(16) u16 As[128 * 64];
  __shared__ __align__(16) u16 Bs[128 * 64];
  const int tid = threadIdx.x, lane = tid & 63, w = tid >> 6;
  const int wr = w >> 1, wc = w & 1, lr = lane & 15, lg = lane >> 4;
  const int bm = blockIdx.x, bn = blockIdx.y;
  const u16* Ag = A + (size_t)bm * 128 * K;
  const u16* Bg = Bt + (size_t)bn * 128 * K;
  f32x4 acc[4][4];
#pragma unroll
  for (int m = 0; m < 4; ++m)
#pragma unroll
    for (int n = 0; n < 4; ++n) acc[m][n] = (f32x4){0.f, 0.f, 0.f, 0.f};

  for (int k0 = 0; k0 < K; k0 += 64) {
#pragma unroll
    for (int it = 0; it < 4; ++it) {
      int chunk = it * 256 + w * 64 + lane;
      int r = chunk >> 3, kc = chunk & 7;
      __builtin_amdgcn_global_load_lds(AS1(Ag + (size_t)r * K + k0 + kc * 8),
                                       AS3(As + (it * 256 + w * 64) * 8), 16, 0, 0);
      __builtin_amdgcn_global_load_lds(AS1(Bg + (size_t)r * K + k0 + kc * 8),
                                       AS3(Bs + (it * 256 + w * 64) * 8), 16, 0, 0);
    }
    __syncthreads();
#pragma unroll
    for (int kk = 0; kk < 2; ++kk) {
      bf16x8 a[4], b[4];
#pragma unroll
      for (int m = 0; m < 4; ++m)
        a[m] = *(const bf16x8*)&As[(wr * 64 + m * 16 + lr) * 64 + kk * 32 + lg * 8];
#pragma unroll
      for (int n = 0; n < 4; ++n)
        b[n] = *(const bf16x8*)&Bs[(wc * 64 + n * 16 + lr) * 64 + kk * 32 + lg * 8];
#pragma unroll
      for (int m = 0; m < 4; ++m)
#pragma unroll
        for (int n = 0; n < 4; ++n)
          acc[m][n] = __builtin_amdgcn_mfma_f32_16x16x32_bf16(a[m], b[n], acc[m][n], 0, 0, 0);
    }
    __syncthreads();
  }
#pragma unroll
  for (int m = 0; m < 4; ++m)
#pragma unroll
    for (int n = 0; n < 4; ++n)
#pragma unroll
      for (int r = 0; r < 4; ++r) {
        int row = bm * 128 + wr * 64 + m * 16 + lg * 4 + r;
        int col = bn * 128 + wc * 64 + n * 16 + lr;
        float v = acc[m][n][r] + bvec[col];
        if (MODE == 0) {
          if (col < 512) v *= SCALE;
          ((u16*)outp)[(size_t)row * NDIM + col] = f2b(v);
        } else {
          ((float*)outp)[(size_t)row * NDIM + col] = v;
        }
      }
}

// ---------------- fused attention: block = (h, qb) x 8 batches ----------------
__global__ __launch_bounds__(256, 2) void attn_kernel(const u16* __restrict__ qkv,
                                                      const u16* __restrict__ bias2,
                                                      const u16* __restrict__ mod2,
                                                      u16* __restrict__ attnout) {
  __shared__ __align__(16) u16 Ks[256 * 32];
  __shared__ __align__(16) u16 Vt[32 * 256];
  __shared__ __align__(16) u16 Ps[64 * 256];
  // XCD-chunked logical id: consecutive logicals land on the same XCD
  const int logical = ((blockIdx.x & 7) << 7) + (blockIdx.x >> 3);   // 1024 blocks
  const int bg = logical >> 6;          // 0..15 (batch group of 8)
  const int h  = (logical >> 2) & 15;
  const int qb = logical & 3;
  const int tid = threadIdx.x, lane = tid & 63, w = tid >> 6;
  const int lr = lane & 15, lg = lane >> 4;
  const int rb = qb * 4 + w;            // row-block 0..15 (16 query rows)
  const int n0 = rb * 16;

  // bias fragment -> f32 regs (used as MFMA C-in); mod stays packed
  f32x4 biasC[16];
  {
    u32 bw[32];
    const uint4* bp = (const uint4*)(bias2 + ((size_t)((h * 16 + rb) * 64 + lane) << 6));
#pragma unroll
    for (int j = 0; j < 8; ++j) *(uint4*)&bw[j * 4] = bp[j];
#pragma unroll
    for (int t = 0; t < 16; ++t)
#pragma unroll
      for (int r = 0; r < 4; ++r) {
        int idx = t * 4 + r;
        u32 wd = bw[idx >> 1];
        biasC[t][r] = (idx & 1) ? __uint_as_float(wd & 0xffff0000u)
                                : __uint_as_float(wd << 16);
      }
  }
  u32 mw[32];
  {
    const uint4* mp = (const uint4*)(mod2 + ((size_t)(rb * 64 + lane) << 6));
#pragma unroll
    for (int j = 0; j < 8; ++j) *(uint4*)&mw[j * 4] = mp[j];
  }

  for (int g = 0; g < 8; ++g) {
    const int b = bg * 8 + g;
    const u16* base = qkv + (size_t)b * TOK * QKVC;
    // V row -> regs (transposed scatter below)
    const u16* vrow = base + (size_t)tid * QKVC + 1024 + h * 32;
    uint4 tv0 = *(const uint4*)(vrow);
    uint4 tv1 = *(const uint4*)(vrow + 8);
    uint4 tv2 = *(const uint4*)(vrow + 16);
    uint4 tv3 = *(const uint4*)(vrow + 24);
    // Q fragment (pre-scaled in qkv epilogue)
    bf16x8 qf = *(const bf16x8*)(base + (size_t)(n0 + lr) * QKVC + h * 32 + lg * 8);
    // K -> LDS direct
    const u16* kbase = base + 512 + h * 32;
#pragma unroll
    for (int it = 0; it < 4; ++it) {
      int chunk = it * 256 + w * 64 + lane;
      int r_ = chunk >> 2, seg = chunk & 3;
      __builtin_amdgcn_global_load_lds(AS1(kbase + (size_t)r_ * QKVC + seg * 8),
                                       AS3(Ks + (it * 256 + w * 64) * 8), 16, 0, 0);
    }
    // V^T scatter (2 lanes per dword -> conflict-free)
    {
      u16 tmp[32];
      *(uint4*)&tmp[0] = tv0; *(uint4*)&tmp[8] = tv1;
      *(uint4*)&tmp[16] = tv2; *(uint4*)&tmp[24] = tv3;
#pragma unroll
      for (int d = 0; d < 32; ++d) Vt[d * 256 + tid] = tmp[d];
    }
    __syncthreads();

    // S = Q K^T + bias (bias as C-in)
    f32x4 s[16];
#pragma unroll
    for (int t = 0; t < 16; ++t) {
      bf16x8 kf = *(const bf16x8*)&Ks[(t * 16 + lr) * 32 + lg * 8];
      s[t] = __builtin_amdgcn_mfma_f32_16x16x32_bf16(qf, kf, biasC[t], 0, 0, 0);
    }

    // softmax over m: in-lane over t, cross-lane over lr (16 lanes)
    float mx[4], sm[4];
#pragma unroll
    for (int r = 0; r < 4; ++r) {
      float m = s[0][r];
#pragma unroll
      for (int t = 1; t < 16; ++t) m = fmaxf(m, s[t][r]);
#pragma unroll
      for (int off = 1; off < 16; off <<= 1) m = fmaxf(m, __shfl_xor(m, off, 64));
      mx[r] = m;
      sm[r] = 0.f;
    }
#pragma unroll
    for (int t = 0; t < 16; ++t)
#pragma unroll
      for (int r = 0; r < 4; ++r) {
        s[t][r] = __expf(s[t][r] - mx[r]);
        sm[r] += s[t][r];
      }
#pragma unroll
    for (int r = 0; r < 4; ++r) {
#pragma unroll
      for (int off = 1; off < 16; off <<= 1) sm[r] += __shfl_xor(sm[r], off, 64);
      sm[r] = __builtin_amdgcn_rcpf(sm[r]);
    }

    // P = softmax * mod -> swizzled LDS tile (bf16)
#pragma unroll
    for (int t = 0; t < 16; ++t)
#pragma unroll
      for (int r = 0; r < 4; ++r) {
        int idx = t * 4 + r;
        u32 wd = mw[idx >> 1];
        float mf = (idx & 1) ? __uint_as_float(wd & 0xffff0000u)
                             : __uint_as_float(wd << 16);
        float pv = s[t][r] * sm[r] * mf;
        int wrow = lg * 4 + r;
        int cs = (t * 2 + (lr >> 3)) ^ (wrow & 7);
        Ps[(w * 16 + wrow) * 256 + cs * 8 + (lr & 7)] = f2bc(pv);
      }

    // O = P V  (per-wave P region; no barrier needed, lgkmcnt ordering only)
    f32x4 o0 = (f32x4){0.f, 0.f, 0.f, 0.f};
    f32x4 o1 = (f32x4){0.f, 0.f, 0.f, 0.f};
#pragma unroll
    for (int kk = 0; kk < 8; ++kk) {
      int cs = (kk * 4 + lg) ^ (lr & 7);
      bf16x8 pa = *(const bf16x8*)&Ps[(w * 16 + lr) * 256 + cs * 8];
      bf16x8 v0 = *(const bf16x8*)&Vt[lr * 256 + kk * 32 + lg * 8];
      bf16x8 v1 = *(const bf16x8*)&Vt[(16 + lr) * 256 + kk * 32 + lg * 8];
      o0 = __builtin_amdgcn_mfma_f32_16x16x32_bf16(pa, v0, o0, 0, 0, 0);
      o1 = __builtin_amdgcn_mfma_f32_16x16x32_bf16(pa, v1, o1, 0, 0, 0);
    }
    u16* orow = attnout + (size_t)(b * TOK + n0) * CDIM + h * 32;
#pragma unroll
    for (int r = 0; r < 4; ++r) {
      orow[(size_t)(lg * 4 + r) * CDIM + lr] = f2bc(o0[r]);
      orow[(size_t)(lg * 4 + r) * CDIM + 16 + lr] = f2bc(o1[r]);
    }
    if (g < 7) __syncthreads();   // protect Ks/Vt before next stage
  }
}

// ---------------- launch ----------------
extern "C" void kernel_launch(void* const* d_in, const int* in_sizes, int n_in,
                              void* d_out, int out_size, void* d_ws, size_t ws_size,
                              hipStream_t stream) {
  const float* x      = (const float*)d_in[0];
  const float* qkv_w  = (const float*)d_in[1];
  const float* qkv_b  = (const float*)d_in[2];
  const float* proj_w = (const float*)d_in[3];
  const float* proj_b = (const float*)d_in[4];
  const float* rpb    = (const float*)d_in[5];

  char* ws = (char*)d_ws;
  u16* xb     = (u16*)(ws);                 // 33,554,432 B
  u16* qkvwb  = (u16*)(ws + 33554432);      //  1,572,864 B
  u16* projwb = (u16*)(ws + 35127296);      //    524,288 B
  u16* qkvbuf = (u16*)(ws + 35651584);      // 100,663,296 B
  u16* attnb  = (u16*)(ws + 136314880);     // 33,554,432 B
  u16* bias2  = (u16*)(ws + 169869312);     //  2,097,152 B
  u16* mod2   = (u16*)(ws + 171966464);     //    131,072 B

  cvt_bf16_kernel<<<8192, 256, 0, stream>>>(x, xb, 32768 * 512);
  cvt_bf16_kernel<<<384, 256, 0, stream>>>(qkv_w, qkvwb, 1536 * 512);
  cvt_bf16_kernel<<<128, 256, 0, stream>>>(proj_w, projwb, 512 * 512);
  build_bias2_kernel<<<4096, 256, 0, stream>>>(rpb, bias2);
  build_mod2_kernel<<<256, 256, 0, stream>>>(mod2);

  gemm_bt<QKVC, 0><<<dim3(256, 12), 256, 0, stream>>>(xb, qkvwb, qkv_b, qkvbuf);
  attn_kernel<<<1024, 256, 0, stream>>>(qkvbuf, bias2, mod2, attnb);
  gemm_bt<CDIM, 1><<<dim3(256, 4), 256, 0, stream>>>(attnb, projwb, proj_b, d_out);
}

// Round 3
// 257.552 us; speedup vs baseline: 1.6320x; 1.6320x over previous
//
#include <hip/hip_runtime.h>
#include <hip/hip_bf16.h>

typedef unsigned short u16;
typedef unsigned int u32;
typedef __bf16 bf16x8 __attribute__((ext_vector_type(8)));
typedef float f32x4 __attribute__((ext_vector_type(4)));

#define AS1(p) ((const __attribute__((address_space(1))) void*)(p))
#define AS3(p) ((__attribute__((address_space(3))) void*)(p))

#define BATCH 128
#define TOK   256
#define NH    16
#define HD    32
#define CDIM  512
#define QKVC  1536
#define SCALE 0.17677669529663687f

__device__ __forceinline__ u16 f2b(float f) {
  unsigned u = __float_as_uint(f);
  unsigned r = (u + 0x7fffu + ((u >> 16) & 1u)) >> 16;
  return (u16)r;
}
__device__ __forceinline__ u16 f2bc(float f) {
  __bf16 h = (__bf16)f;
  u16 u;
  __builtin_memcpy(&u, &h, 2);
  return u;
}
__device__ __forceinline__ float bl(u32 wd) { return __uint_as_float(wd << 16); }
__device__ __forceinline__ float bh(u32 wd) { return __uint_as_float(wd & 0xffff0000u); }

// ---------------- fp32 -> bf16 conversion ----------------
__global__ __launch_bounds__(256) void cvt_bf16_kernel(const float* __restrict__ in,
                                                       u16* __restrict__ out, int n) {
  int i = (blockIdx.x * 256 + threadIdx.x) * 8;
  if (i >= n) return;
  float4 a = *(const float4*)(in + i);
  float4 b = *(const float4*)(in + i + 4);
  u16 h[8];
  h[0] = f2b(a.x); h[1] = f2b(a.y); h[2] = f2b(a.z); h[3] = f2b(a.w);
  h[4] = f2b(b.x); h[5] = f2b(b.y); h[6] = f2b(b.z); h[7] = f2b(b.w);
  *(uint4*)(out + i) = *(const uint4*)h;
}

// ---------------- bias2: S^T fragment layout, bf16 ----------------
// lane holds S^T tile t: row m = t*16 + lg*4 + r, col n = rb*16 + lr
__global__ __launch_bounds__(256) void build_bias2_kernel(const float* __restrict__ rpb,
                                                          u16* __restrict__ bias2) {
  int i = blockIdx.x * 256 + threadIdx.x;   // 16*16*64*64 = 2^20
  int tr = i & 63, lane = (i >> 6) & 63, rb = (i >> 12) & 15, h = i >> 16;
  int t = tr >> 2, r = tr & 3;
  int n = rb * 16 + (lane & 15);
  int m = t * 16 + (lane >> 4) * 4 + r;
  int idx = ((n >> 4) - (m >> 4) + 15) * 31 + ((n & 15) - (m & 15) + 15);
  bias2[i] = f2b(rpb[idx * 16 + h]);
}

// ---------------- mod2: S^T fragment layout, bf16 ----------------
__global__ __launch_bounds__(256) void build_mod2_kernel(u16* __restrict__ mod2) {
  int i = blockIdx.x * 256 + threadIdx.x;   // 16*64*64 = 65536
  int tr = i & 63, lane = (i >> 6) & 63, rb = i >> 12;
  int t = tr >> 2, r = tr & 3;
  int n = rb * 16 + (lane & 15);
  int m = t * 16 + (lane >> 4) * 4 + r;
  int dr = (n >> 4) - (m >> 4), dc = (n & 15) - (m & 15);
  int d2 = dr * dr + dc * dc;
  float val = 0.0f;
  if (d2 <= 229) {   // exact integer form of (m >= bound); boundary at d2==229
    const float fc = 6.2831853071795864f / (60.0f * 1.4142135623730951f);
    val = expf(cosf(fc * sqrtf((float)d2))) * 0.5f;
  }
  mod2[i] = f2b(val);
}

// ---------------- bf16 GEMM: out = A[M,K] @ Bt[N,K]^T (+bias epilogue) ----------------
template<int NDIM, int MODE>
__global__ __launch_bounds__(256) void gemm_bt(const u16* __restrict__ A,
                                               const u16* __restrict__ Bt,
                                               const float* __restrict__ bvec,
                                               void* __restrict__ outp) {
  constexpr int K = 512;
  __shared__ __align__(16) u16 As[128 * 64];
  __shared__ __align__(16) u16 Bs[128 * 64];
  const int tid = threadIdx.x, lane = tid & 63, w = tid >> 6;
  const int wr = w >> 1, wc = w & 1, lr = lane & 15, lg = lane >> 4;
  const int bm = blockIdx.x, bn = blockIdx.y;
  const u16* Ag = A + (size_t)bm * 128 * K;
  const u16* Bg = Bt + (size_t)bn * 128 * K;
  f32x4 acc[4][4];
#pragma unroll
  for (int m = 0; m < 4; ++m)
#pragma unroll
    for (int n = 0; n < 4; ++n) acc[m][n] = (f32x4){0.f, 0.f, 0.f, 0.f};

  for (int k0 = 0; k0 < K; k0 += 64) {
#pragma unroll
    for (int it = 0; it < 4; ++it) {
      int chunk = it * 256 + w * 64 + lane;
      int r = chunk >> 3, kc = chunk & 7;
      __builtin_amdgcn_global_load_lds(AS1(Ag + (size_t)r * K + k0 + kc * 8),
                                       AS3(As + (it * 256 + w * 64) * 8), 16, 0, 0);
      __builtin_amdgcn_global_load_lds(AS1(Bg + (size_t)r * K + k0 + kc * 8),
                                       AS3(Bs + (it * 256 + w * 64) * 8), 16, 0, 0);
    }
    __syncthreads();
#pragma unroll
    for (int kk = 0; kk < 2; ++kk) {
      bf16x8 a[4], b[4];
#pragma unroll
      for (int m = 0; m < 4; ++m)
        a[m] = *(const bf16x8*)&As[(wr * 64 + m * 16 + lr) * 64 + kk * 32 + lg * 8];
#pragma unroll
      for (int n = 0; n < 4; ++n)
        b[n] = *(const bf16x8*)&Bs[(wc * 64 + n * 16 + lr) * 64 + kk * 32 + lg * 8];
#pragma unroll
      for (int m = 0; m < 4; ++m)
#pragma unroll
        for (int n = 0; n < 4; ++n)
          acc[m][n] = __builtin_amdgcn_mfma_f32_16x16x32_bf16(a[m], b[n], acc[m][n], 0, 0, 0);
    }
    __syncthreads();
  }
#pragma unroll
  for (int m = 0; m < 4; ++m)
#pragma unroll
    for (int n = 0; n < 4; ++n)
#pragma unroll
      for (int r = 0; r < 4; ++r) {
        int row = bm * 128 + wr * 64 + m * 16 + lg * 4 + r;
        int col = bn * 128 + wc * 64 + n * 16 + lr;
        float v = acc[m][n][r] + bvec[col];
        if (MODE == 0) {
          if (col < 512) v *= SCALE;
          ((u16*)outp)[(size_t)row * NDIM + col] = f2b(v);
        } else {
          ((float*)outp)[(size_t)row * NDIM + col] = v;
        }
      }
}

// ---------------- fused attention: one (b,h,qb) per block, S^T form ----------------
__global__ __launch_bounds__(256, 3) void attn_kernel(const u16* __restrict__ qkv,
                                                      const u16* __restrict__ bias2,
                                                      const u16* __restrict__ mod2,
                                                      u16* __restrict__ attnout) {
  __shared__ __align__(16) u16 Ks[256 * 32];            // 16 KB
  __shared__ __align__(16) u16 Vt[32 * 256];            // 16 KB (swizzled)
  __shared__ __align__(16) u16 Ps[4 * 16 * 128];        // 16 KB (half-P, swizzled)
  // XCD-chunked: each XCD owns 2 heads; (h,b) quads adjacent for K/V L2 reuse
  const int logical = ((blockIdx.x & 7) << 10) + (blockIdx.x >> 3);   // 8192 blocks
  const int h  = logical >> 9;
  const int rem = logical & 511;
  const int b  = rem >> 2;
  const int qb = rem & 3;
  const int tid = threadIdx.x, lane = tid & 63, w = tid >> 6;
  const int lr = lane & 15, lg = lane >> 4;
  const int rb = qb * 4 + w;
  const int n0 = rb * 16;
  const u16* base = qkv + (size_t)b * TOK * QKVC;

  // packed bias/mod fragments (u32 = 2 bf16)
  u32 bw[32], mw[32];
  {
    const uint4* bp = (const uint4*)(bias2 + ((size_t)((h * 16 + rb) * 64 + lane) << 6));
    const uint4* mp = (const uint4*)(mod2 + ((size_t)(rb * 64 + lane) << 6));
#pragma unroll
    for (int j = 0; j < 8; ++j) { *(uint4*)&bw[j * 4] = bp[j]; *(uint4*)&mw[j * 4] = mp[j]; }
  }

  // K -> LDS direct (linear [256][32])
  const u16* kbase = base + 512 + h * 32;
#pragma unroll
  for (int it = 0; it < 4; ++it) {
    int chunk = it * 256 + w * 64 + lane;
    int r_ = chunk >> 2, seg = chunk & 3;
    __builtin_amdgcn_global_load_lds(AS1(kbase + (size_t)r_ * QKVC + seg * 8),
                                     AS3(Ks + (it * 256 + w * 64) * 8), 16, 0, 0);
  }
  // V^T scatter, chunk-swizzled: byte = d*512 + ((m>>3)^(d&7))*16 + (m&7)*2
  {
    const u16* vrow = base + (size_t)tid * QKVC + 1024 + h * 32;
    u16 tmp[32];
    *(uint4*)&tmp[0]  = *(const uint4*)(vrow);
    *(uint4*)&tmp[8]  = *(const uint4*)(vrow + 8);
    *(uint4*)&tmp[16] = *(const uint4*)(vrow + 16);
    *(uint4*)&tmp[24] = *(const uint4*)(vrow + 24);
    char* vb = (char*)Vt;
    int mhi = (tid >> 3), mlo2 = (tid & 7) * 2;
#pragma unroll
    for (int d = 0; d < 32; ++d)
      *(u16*)(vb + d * 512 + ((mhi ^ (d & 7)) << 4) + mlo2) = tmp[d];
  }
  // Q fragment (B-operand): Q[n0+lr][lg*8..]
  bf16x8 qf = *(const bf16x8*)(base + (size_t)(n0 + lr) * QKVC + h * 32 + lg * 8);
  __syncthreads();

  // S^T = K Q^T + bias: lane holds S^T[m = t*16+lg*4+r][n = n0+lr]
  f32x4 s[16];
#pragma unroll
  for (int t = 0; t < 16; ++t) {
    bf16x8 kf = *(const bf16x8*)&Ks[(t * 16 + lr) * 32 + lg * 8];
    f32x4 c;
#pragma unroll
    for (int r = 0; r < 4; ++r) {
      u32 wd = bw[t * 2 + (r >> 1)];
      c[r] = (r & 1) ? bh(wd) : bl(wd);
    }
    s[t] = __builtin_amdgcn_mfma_f32_16x16x32_bf16(kf, qf, c, 0, 0, 0);
  }

  // softmax over m for col n=lr: in-lane 64 + xor16 + xor32
  float mx = s[0][0];
#pragma unroll
  for (int t = 0; t < 16; ++t)
#pragma unroll
    for (int r = 0; r < 4; ++r) mx = fmaxf(mx, s[t][r]);
  mx = fmaxf(mx, __shfl_xor(mx, 16, 64));
  mx = fmaxf(mx, __shfl_xor(mx, 32, 64));
  float sm = 0.f;
#pragma unroll
  for (int t = 0; t < 16; ++t)
#pragma unroll
    for (int r = 0; r < 4; ++r) {
      s[t][r] = __expf(s[t][r] - mx);
      sm += s[t][r];
    }
  sm += __shfl_xor(sm, 16, 64);
  sm += __shfl_xor(sm, 32, 64);
  sm = __builtin_amdgcn_rcpf(sm);

  // two halves: pack P (b64 swizzled) then PV over that half
  f32x4 o0 = (f32x4){0.f, 0.f, 0.f, 0.f};
  f32x4 o1 = (f32x4){0.f, 0.f, 0.f, 0.f};
  char* prow = (char*)Ps + (w * 16 + lr) * 256;
  const char* vrow_b = (const char*)Vt;
#pragma unroll
  for (int half = 0; half < 2; ++half) {
#pragma unroll
    for (int tr_ = 0; tr_ < 8; ++tr_) {
      int t = half * 8 + tr_;
      u16 pk[4];
#pragma unroll
      for (int r = 0; r < 4; ++r) {
        u32 wd = mw[t * 2 + (r >> 1)];
        float mf = (r & 1) ? bh(wd) : bl(wd);
        pk[r] = f2bc(s[t][r] * sm * mf);
      }
      int g8 = (tr_ * 4 + lg) ^ ((lr & 7) << 1);
      *(uint2*)(prow + g8 * 8) = *(const uint2*)pk;
    }
#pragma unroll
    for (int kkr = 0; kkr < 4; ++kkr) {
      int c16 = (kkr * 4 + lg) ^ (lr & 7);
      bf16x8 pa = *(const bf16x8*)(prow + c16 * 16);
      int kk = half * 4 + kkr;
      int cv = (kk * 4 + lg) ^ (lr & 7);
      bf16x8 v0 = *(const bf16x8*)(vrow_b + lr * 512 + cv * 16);
      bf16x8 v1 = *(const bf16x8*)(vrow_b + (16 + lr) * 512 + cv * 16);
      o0 = __builtin_amdgcn_mfma_f32_16x16x32_bf16(pa, v0, o0, 0, 0, 0);
      o1 = __builtin_amdgcn_mfma_f32_16x16x32_bf16(pa, v1, o1, 0, 0, 0);
    }
  }
  u16* orow = attnout + (size_t)(b * TOK + n0) * CDIM + h * 32;
#pragma unroll
  for (int r = 0; r < 4; ++r) {
    orow[(size_t)(lg * 4 + r) * CDIM + lr] = f2bc(o0[r]);
    orow[(size_t)(lg * 4 + r) * CDIM + 16 + lr] = f2bc(o1[r]);
  }
}

// ---------------- launch ----------------
extern "C" void kernel_launch(void* const* d_in, const int* in_sizes, int n_in,
                              void* d_out, int out_size, void* d_ws, size_t ws_size,
                              hipStream_t stream) {
  const float* x      = (const float*)d_in[0];
  const float* qkv_w  = (const float*)d_in[1];
  const float* qkv_b  = (const float*)d_in[2];
  const float* proj_w = (const float*)d_in[3];
  const float* proj_b = (const float*)d_in[4];
  const float* rpb    = (const float*)d_in[5];

  char* ws = (char*)d_ws;
  u16* xb     = (u16*)(ws);                 // 33,554,432 B
  u16* qkvwb  = (u16*)(ws + 33554432);      //  1,572,864 B
  u16* projwb = (u16*)(ws + 35127296);      //    524,288 B
  u16* qkvbuf = (u16*)(ws + 35651584);      // 100,663,296 B
  u16* attnb  = (u16*)(ws + 136314880);     // 33,554,432 B
  u16* bias2  = (u16*)(ws + 169869312);     //  2,097,152 B
  u16* mod2   = (u16*)(ws + 171966464);     //    131,072 B

  cvt_bf16_kernel<<<8192, 256, 0, stream>>>(x, xb, 32768 * 512);
  cvt_bf16_kernel<<<384, 256, 0, stream>>>(qkv_w, qkvwb, 1536 * 512);
  cvt_bf16_kernel<<<128, 256, 0, stream>>>(proj_w, projwb, 512 * 512);
  build_bias2_kernel<<<4096, 256, 0, stream>>>(rpb, bias2);
  build_mod2_kernel<<<256, 256, 0, stream>>>(mod2);

  gemm_bt<QKVC, 0><<<dim3(256, 12), 256, 0, stream>>>(xb, qkvwb, qkv_b, qkvbuf);
  attn_kernel<<<8192, 256, 0, stream>>>(qkvbuf, bias2, mod2, attnb);
  gemm_bt<CDIM, 1><<<dim3(256, 4), 256, 0, stream>>>(attnb, projwb, proj_b, d_out);
}